// Round 11
// baseline (141.282 us; speedup 1.0000x reference)
//
#include <hip/hip_runtime.h>

using u16 = unsigned short;
using u32 = unsigned int;

typedef __attribute__((ext_vector_type(4))) float f32x4;
typedef __attribute__((ext_vector_type(4))) u16 u16x4;
typedef __attribute__((ext_vector_type(8))) u16 u16x8;
typedef __attribute__((ext_vector_type(8))) short s16x8;

__device__ __forceinline__ u16 f2bf(float f) {
  u32 x = __builtin_bit_cast(u32, f);
  x += 0x7fffu + ((x >> 16) & 1u);
  return (u16)(x >> 16);
}
__device__ __forceinline__ float bf2f(u16 u) {
  u32 x = ((u32)u) << 16;
  return __builtin_bit_cast(float, x);
}

// async global->LDS, 16B per lane. dst must be wave-uniform; HW adds lane*16.
__device__ __forceinline__ void glds16(const u16* gsrc, u16* ldst) {
  __builtin_amdgcn_global_load_lds(
      (const __attribute__((address_space(1))) unsigned int*)gsrc,
      (__attribute__((address_space(3))) unsigned int*)ldst, 16, 0, 0);
}

// ---------------------------------------------------------------------------
// K_prep: blk<144 -> Wb row; blk>=144 -> APre slice for di=blk-144.
// ---------------------------------------------------------------------------
__global__ __launch_bounds__(256) void k_prep(
    const float* __restrict__ wq, const float* __restrict__ wk,
    const float* __restrict__ wv, const float* __restrict__ R,
    u16* __restrict__ Wb, u16* __restrict__ APre)
{
  const int blk = blockIdx.x;
  const int t = threadIdx.x;
  if (blk < 144) {
    const int o = blk;
    const float* src = (o < 64) ? (wq + o * 256)
                     : (o < 80) ? (wk + (o - 64) * 256)
                                : (wv + (o - 80) * 256);
    Wb[o * 256 + t] = f2bf(src[t]);
  } else {
    const int di = blk - 144;
    const int w = t >> 6, l = t & 63;
    const int g = l >> 4, k = l & 15;
    for (int j1 = w; j1 < 32; j1 += 4) {
      u16x8 o8;
#pragma unroll
      for (int e = 0; e < 8; ++e) {
        int dj = 8 * g + e - j1 + 31;
        o8[e] = f2bf(R[(di * 63 + dj) * 16 + k]);
      }
      *(u16x8*)(APre + ((di * 32 + j1) * 64 + l) * 8) = o8;
    }
  }
}

// ---------------------------------------------------------------------------
// K1: 1x1 conv projections via MFMA + fused BN partial sums for q,v.
// ---------------------------------------------------------------------------
union ProjSmem {
  u16 XLb[64][264];
  float SS[2][160];
};

__global__ __launch_bounds__(256) void k_proj(
    const float* __restrict__ x, const u16* __restrict__ Wb,
    float* __restrict__ q_raw, float* __restrict__ k_raw,
    float* __restrict__ v_raw,
    float* __restrict__ qs1, float* __restrict__ qs2,
    float* __restrict__ vs1, float* __restrict__ vs2)
{
  __shared__ ProjSmem PS;
  const int b  = blockIdx.x >> 4;
  const int p0 = (blockIdx.x & 15) * 64;
  const int t  = threadIdx.x;

  {
    const int p4 = (t & 15) * 4;
    const int cb = (t >> 4);
#pragma unroll
    for (int i = 0; i < 8; ++i) {
      const int c = 2 * (i * 16 + cb);
      f32x4 xa = *(const f32x4*)&x[(b * 256 + c) * 1024 + p0 + p4];
      f32x4 xb = *(const f32x4*)&x[(b * 256 + c + 1) * 1024 + p0 + p4];
#pragma unroll
      for (int j = 0; j < 4; ++j) {
        u32 pk = (u32)f2bf(xa[j]) | ((u32)f2bf(xb[j]) << 16);
        *(u32*)&PS.XLb[p4 + j][c] = pk;
      }
    }
  }
  __syncthreads();

  const int w  = t >> 6;
  const int l  = t & 63;
  const int g  = l >> 4;
  const int cc = l & 15;
  const int p  = p0 + w * 16 + cc;

  f32x4 acc[9];
  const f32x4 fz = {0.f, 0.f, 0.f, 0.f};
#pragma unroll
  for (int mt = 0; mt < 9; ++mt) acc[mt] = fz;

#pragma unroll
  for (int ko = 0; ko < 8; ++ko) {
    s16x8 bfr = *(const s16x8*)&PS.XLb[w * 16 + cc][ko * 32 + g * 8];
#pragma unroll
    for (int mt = 0; mt < 9; ++mt) {
      s16x8 afr = *(const s16x8*)&Wb[(mt * 16 + cc) * 256 + ko * 32 + g * 8];
      acc[mt] = __builtin_amdgcn_mfma_f32_16x16x32_bf16(afr, bfr, acc[mt], 0, 0, 0);
    }
  }

#pragma unroll
  for (int mt = 0; mt < 9; ++mt) {
#pragma unroll
    for (int r = 0; r < 4; ++r) {
      const int o = mt * 16 + 4 * g + r;
      const float val = acc[mt][r];
      if (mt < 4)       q_raw[(b * 64 + o) * 1024 + p] = val;
      else if (mt == 4) k_raw[(b * 16 + (o - 64)) * 1024 + p] = val;
      else              v_raw[(b * 64 + (o - 80)) * 1024 + p] = val;
    }
  }

  // ---- fused BN stats epilogue (q: mt 0..3, v: mt 5..8)
  __syncthreads();   // all XLb reads done; reuse LDS as SS
  {
    float* ss = &PS.SS[0][0];
    for (int i = t; i < 320; i += 256) ss[i] = 0.f;
  }
  __syncthreads();
#pragma unroll
  for (int mt = 0; mt < 9; ++mt) {
    if (mt == 4) continue;
#pragma unroll
    for (int r = 0; r < 4; ++r) {
      float s1 = acc[mt][r];
      float s2 = s1 * s1;
#pragma unroll
      for (int off = 1; off < 16; off <<= 1) {
        s1 += __shfl_xor(s1, off);
        s2 += __shfl_xor(s2, off);
      }
      if (cc == 0) {
        const int o = mt * 16 + 4 * g + r;
        atomicAdd(&PS.SS[0][o], s1);
        atomicAdd(&PS.SS[1][o], s2);
      }
    }
  }
  __syncthreads();
  if (t < 64) {
    atomicAdd(&qs1[t], PS.SS[0][t]);
    atomicAdd(&qs2[t], PS.SS[1][t]);
  } else if (t >= 80 && t < 144) {
    atomicAdd(&vs1[t - 80], PS.SS[0][t]);
    atomicAdd(&vs2[t - 80], PS.SS[1][t]);
  }
}

// ---------------------------------------------------------------------------
// K_nl2: fused k-softmax stats (in-block; k_raw is 2MB L2-resident so the
// 8x re-read is ~free) + V-normalize + vnF write + lam_c partial.
// ---------------------------------------------------------------------------
__global__ __launch_bounds__(256) void k_nl(
    const float* __restrict__ v_raw,
    const float* __restrict__ vs1, const float* __restrict__ vs2,
    const float* __restrict__ gv, const float* __restrict__ bv,
    const float* __restrict__ k_raw,
    u16* __restrict__ vnF, float* __restrict__ lam_c)
{
  __shared__ float VN[64][136];
  __shared__ float KE[16][132];
  __shared__ float KMX[16], KIV[16];
  const int b  = blockIdx.x >> 3;
  const int m0 = (blockIdx.x & 7) * 128;
  const int t  = threadIdx.x;
  const int wv4 = t >> 6, lane = t & 63;

  // ---- full-row softmax stats for this b's 16 k-rows (one wave per row)
  for (int rr = wv4; rr < 16; rr += 4) {
    const int row = b * 16 + rr;
    const f32x4* kr4 = (const f32x4*)(k_raw + row * 1024 + lane * 16);
    f32x4 a0 = kr4[0], a1 = kr4[1], a2 = kr4[2], a3 = kr4[3];
    float mx = -3.0e38f;
#pragma unroll
    for (int j = 0; j < 4; ++j)
      mx = fmaxf(mx, fmaxf(fmaxf(a0[j], a1[j]), fmaxf(a2[j], a3[j])));
#pragma unroll
    for (int off = 32; off; off >>= 1) mx = fmaxf(mx, __shfl_xor(mx, off));
    float s = 0.f;
#pragma unroll
    for (int j = 0; j < 4; ++j)
      s += __expf(a0[j] - mx) + __expf(a1[j] - mx)
         + __expf(a2[j] - mx) + __expf(a3[j] - mx);
#pragma unroll
    for (int off = 32; off; off >>= 1) s += __shfl_xor(s, off);
    if (lane == 0) { KMX[rr] = mx; KIV[rr] = 1.0f / s; }
  }

  // ---- V-normalize + vnF write (independent of stats; before barrier)
  {
    const int v = t & 63, mseg = t >> 6;   // 32 m per thread
    const float invN = 1.0f / 32768.0f;
    const float mu = vs1[v] * invN;
    const float var = vs2[v] * invN - mu * mu;
    const float sc = rsqrtf(var + 1e-5f) * gv[v];
    const float bi = bv[v] - mu * sc;
    const int i2 = (m0 >> 5) + mseg;
    const float* src = v_raw + (b * 64 + v) * 1024 + i2 * 32;
    u16* dstF = vnF + ((b * 32 + i2) * 4 + (v >> 4)) * 512 + (v & 15) * 8;
#pragma unroll
    for (int lg = 0; lg < 4; ++lg) {
      f32x4 a = *(const f32x4*)(src + lg * 8);
      f32x4 c = *(const f32x4*)(src + lg * 8 + 4);
      f32x4 na, nc;
      u16x8 o8;
#pragma unroll
      for (int j = 0; j < 4; ++j) {
        na[j] = a[j] * sc + bi;
        nc[j] = c[j] * sc + bi;
        o8[j] = f2bf(na[j]);
        o8[4 + j] = f2bf(nc[j]);
      }
      *(f32x4*)&VN[v][mseg * 32 + lg * 8] = na;
      *(f32x4*)&VN[v][mseg * 32 + lg * 8 + 4] = nc;
      *(u16x8*)(dstF + lg * 128) = o8;
    }
  }
  __syncthreads();   // KMX/KIV + VN visible

  // ---- KE for this m-chunk using in-block stats
  {
    const int kc = t >> 4, mm = (t & 15) * 8;
    const float* kr = k_raw + (b * 16 + kc) * 1024 + m0 + mm;
    const float mx = KMX[kc], iv = KIV[kc];
#pragma unroll
    for (int j = 0; j < 8; ++j) KE[kc][mm + j] = __expf(kr[j] - mx) * iv;
  }
  __syncthreads();

  const int kc = t & 15, vg = t >> 4;
  float acc[4] = {0.f, 0.f, 0.f, 0.f};
  for (int m4 = 0; m4 < 128; m4 += 4) {
    f32x4 ke = *(const f32x4*)&KE[kc][m4];
#pragma unroll
    for (int j = 0; j < 4; ++j) {
      f32x4 vv = *(const f32x4*)&VN[vg * 4 + j][m4];
      acc[j] += ke[0] * vv[0] + ke[1] * vv[1] + ke[2] * vv[2] + ke[3] * vv[3];
    }
  }
#pragma unroll
  for (int j = 0; j < 4; ++j)
    atomicAdd(&lam_c[(b * 16 + kc) * 64 + vg * 4 + j], acc[j]);
}

// ---------------------------------------------------------------------------
// K4 v15: ROW-PAIRED A-SLAB REUSE THROUGH LDS. Model: k_main is L2->CU
// byte-delivery bound (~27 B/cy/CU at 16 waves); A (E-slabs) is 80% of the
// 1.31 GB. Key identity: slab(di) used by row a at step i2 is used by row
// a+1 at the SAME i2 one di earlier -- so a block computing rows {a, a+1}
// with BOTH groups at the same i2 per phase reuses each slab twice with a
// lag of exactly one phase. A goes through a 3-slot rotating LDS buffer
// (read via ds_read_b128 -> zero extra registers, unlike v13/v14's failed
// reg-dup approach); B (same i2 for both groups) stays a plain 2-buf.
// Bytes: 33x16KB A + 128KB B = 656KB per block for 2x v9's output ->
// 672 MB total (half of v9). Block = 512 thr = 8 waves (2 row-groups x 4);
// per-wave tile/acc/epilogue identical to v9. LDS 48K+8K+8.7K = 64.7KB
// (YL overlays slabs) -> 2 blocks/CU = 16 waves/CU, same occupancy as v9.
// Phase: stage(next slab, next B) -> ds_read A/B frags -> 16 MFMA ->
// vmcnt(0) (only own glds outstanding) -> barrier.
// ---------------------------------------------------------------------------
union KMainSmem {
  struct {
    u16 AS[3][8192];   // 48 KB: 3 rotating A slabs (16 j1 x 512 u16 each)
    u16 BB[2][2048];   // 8 KB: B double buffer (one i2 slice, 64v x 32m)
  } st;
  float YL[2][256][18];  // 36.9 KB epilogue transpose buffers (overlay AS)
};

__global__ __launch_bounds__(512, 4) void k_main(
    const u16* __restrict__ APre, const u16* __restrict__ vnF,
    const float* __restrict__ q_raw, const float* __restrict__ lam_c,
    const float* __restrict__ qs1, const float* __restrict__ qs2,
    const float* __restrict__ gq, const float* __restrict__ bq,
    float* __restrict__ out)
{
  __shared__ alignas(16) KMainSmem S;
  __shared__ float QL[2][64][17];   // BN-folded q per row-group
  const int bid  = blockIdx.x;
  const int xcd  = bid & 7;
  const int sb   = bid >> 3;          // 0..127
  const int b    = xcd * 4 + (sb & 3);  // 4 consecutive b's per XCD
  const int rest = sb >> 2;           // 0..31
  const int i1p  = rest >> 1;         // 0..15 (row pair)
  const int half = rest & 1;
  const int a0   = 2 * i1p;           // group0 row; group1 = a0 + 1
  const int h16  = half * 16;
  const int t   = threadIdx.x;
  const int w   = t >> 6;             // 0..7
  const int grp = w >> 2;             // 0: row a0, 1: row a0+1
  const int wl  = w & 3;              // wave within group
  const int l   = t & 63;
  const int g   = l >> 4;
  const int c   = l & 15;

  const u16* vF = vnF + b * 65536;    // 32 i2 * 2048 u16 per b

  f32x4 acc[4][4];
  const f32x4 fz = {0.f, 0.f, 0.f, 0.f};
#pragma unroll
  for (int nn = 0; nn < 4; ++nn)
#pragma unroll
    for (int tt = 0; tt < 4; ++tt) acc[nn][tt] = fz;

  // stage slab(di) -> slot: 16 KB, all 8 waves, 2 glds16 each
  auto stageA = [&](int di, int slot) {
    const u16* asrc = APre + (di * 32 + h16) * 512 + w * 1024 + l * 8;
    u16* adst = &S.st.AS[slot][w * 1024];
    glds16(asrc, adst);
    glds16(asrc + 512, adst + 512);
  };
  // stage B(i2) -> buf: 4 KB, waves 0-3 only, 1 glds16 each
  auto stageB = [&](int i2, int buf) {
    if (w < 4) {
      const u16* bsrc = vF + i2 * 2048 + w * 512 + l * 8;
      glds16(bsrc, &S.st.BB[buf][w * 512]);
    }
  };

  // ---- prologue: two slabs (group1 and group0 phase-0), B(0), QL staging
  stageA(30 - a0, 0);   // di for group1 at i2=0
  stageA(31 - a0, 1);   // di for group0 at i2=0
  stageB(0, 0);
  {
    const int g2 = t >> 8;             // which row-group's q
    const int o  = (t & 255) >> 2;
    const int ns = (t & 3) * 4;
    const float invN = 1.0f / 32768.0f;
    const float mu = qs1[o] * invN;
    const float var = qs2[o] * invN - mu * mu;
    const float sc = rsqrtf(var + 1e-5f) * gq[o];
    const float bi = bq[o] - mu * sc;
    f32x4 qa = *(const f32x4*)&q_raw[(b * 64 + o) * 1024
                                     + (a0 + g2) * 32 + h16 + ns];
#pragma unroll
    for (int j = 0; j < 4; ++j) QL[g2][o][ns + j] = qa[j] * sc + bi;
  }
  __syncthreads();   // drains vmcnt+lgkm: slabs, B, QL all visible

  // ---- main loop: both groups compute i2 = s each phase.
  // group0 reads slot (s+1)%3, group1 reads slot s%3 (one-phase lag);
  // prefetch slab di = 32-a0+s into slot (s+2)%3 (unused this phase).
  for (int s = 0; s < 32; ++s) {
    const int bcur = s & 1;
    if (s < 31) {
      stageA(32 - a0 + s, (s + 2) % 3);
      stageB(s + 1, bcur ^ 1);
    }
    __builtin_amdgcn_sched_barrier(0);   // pin glds issue at phase head
    const int myslot = (s + 1 - grp) % 3;
    s16x8 afr[4], bfr[4];
#pragma unroll
    for (int nn = 0; nn < 4; ++nn)
      afr[nn] = *(const s16x8*)&S.st.AS[myslot][(wl * 4 + nn) * 512 + l * 8];
#pragma unroll
    for (int tt = 0; tt < 4; ++tt)
      bfr[tt] = *(const s16x8*)&S.st.BB[bcur][tt * 512 + l * 8];
#pragma unroll
    for (int nn = 0; nn < 4; ++nn)
#pragma unroll
      for (int tt = 0; tt < 4; ++tt)
        acc[nn][tt] = __builtin_amdgcn_mfma_f32_16x16x32_bf16(
            afr[nn], bfr[tt], acc[nn][tt], 0, 0, 0);
    // only this wave's 2-3 glds are outstanding; drain them, then barrier.
    asm volatile("s_waitcnt vmcnt(0)" ::: "memory");
    __builtin_amdgcn_sched_barrier(0);
    __builtin_amdgcn_s_barrier();
    __builtin_amdgcn_sched_barrier(0);
  }

  // ---- epilogue: lam_c pre-add, q-contract, transpose via YL[grp], store.
  // (AS/BB dead after final barrier; YL overlays AS.)
  {
    const float* lcb = lam_c + b * 1024;
#pragma unroll
    for (int tt = 0; tt < 4; ++tt)
#pragma unroll
      for (int r = 0; r < 4; ++r) {
        const float lv = lcb[(4 * g + r) * 64 + tt * 16 + c];
#pragma unroll
        for (int nn = 0; nn < 4; ++nn) acc[nn][tt][r] += lv;
      }
  }
#pragma unroll
  for (int nn = 0; nn < 4; ++nn) {
    const int j1loc = wl * 4 + nn;
#pragma unroll
    for (int h = 0; h < 4; ++h) {
      const float q0 = QL[grp][h * 16 + 4 * g + 0][j1loc];
      const float q1 = QL[grp][h * 16 + 4 * g + 1][j1loc];
      const float q2 = QL[grp][h * 16 + 4 * g + 2][j1loc];
      const float q3 = QL[grp][h * 16 + 4 * g + 3][j1loc];
#pragma unroll
      for (int tt = 0; tt < 4; ++tt) {
        float sY = q0 * acc[nn][tt][0] + q1 * acc[nn][tt][1]
                 + q2 * acc[nn][tt][2] + q3 * acc[nn][tt][3];
        sY += __shfl_xor(sY, 16);
        sY += __shfl_xor(sY, 32);
        if (g == h) S.YL[grp][h * 64 + tt * 16 + c][j1loc] = sY;
      }
    }
  }
  __syncthreads();
#pragma unroll
  for (int it = 0; it < 4; ++it) {
    const int g2 = t >> 8;
    const int o  = ((t & 255) >> 2) + it * 64;
    const int nf = (t & 3) * 4;
    f32x4 v4 = *(const f32x4*)&S.YL[g2][o][nf];
    *(f32x4*)&out[(b * 256 + o) * 1024 + (a0 + g2) * 32 + h16 + nf] = v4;
  }
}

// ---------------------------------------------------------------------------
extern "C" void kernel_launch(void* const* d_in, const int* in_sizes, int n_in,
                              void* d_out, int out_size, void* d_ws, size_t ws_size,
                              hipStream_t stream) {
  const float* x  = (const float*)d_in[0];
  const float* wq = (const float*)d_in[1];
  const float* wk = (const float*)d_in[2];
  const float* wv = (const float*)d_in[3];
  const float* gq = (const float*)d_in[4];
  const float* bq = (const float*)d_in[5];
  const float* gv = (const float*)d_in[6];
  const float* bv = (const float*)d_in[7];
  const float* R  = (const float*)d_in[8];
  float* out = (float*)d_out;

  float* wsf   = (float*)d_ws;
  float* q_raw = wsf;                     // 32*64*1024 f32
  float* k_raw = q_raw + 32 * 64 * 1024;  // 32*16*1024
  float* v_raw = k_raw + 32 * 16 * 1024;  // 32*64*1024
  float* lam_c = v_raw + 32 * 64 * 1024;  // 32*16*64 (atomic dst, zeroed)
  float* qs1   = lam_c + 32 * 16 * 64;
  float* qs2   = qs1 + 64;
  float* vs1   = qs2 + 64;
  float* vs2   = vs1 + 64;
  float* kmax  = vs2 + 64;                // 512 (unused, keeps offsets stable)
  float* kinv  = kmax + 512;              // 512 (unused)
  u16*   vn    = (u16*)(kinv + 512);      // (unused slot, keeps offsets stable)
  u16*   vnF   = vn + 32 * 64 * 1024;     // 32*65536 u16 (fragment-linear)
  u16*   APre  = vnF + 32 * 65536;        // 63*32*512 u16
  u16*   Wb    = APre + 63 * 32 * 512;    // 144*256 u16

  hipMemsetAsync(lam_c, 0, (32 * 16 * 64 + 256) * sizeof(float), stream);
  k_prep<<<207, 256, 0, stream>>>(wq, wk, wv, R, Wb, APre);
  k_proj<<<512, 256, 0, stream>>>(x, Wb, q_raw, k_raw, v_raw, qs1, qs2, vs1, vs2);
  k_nl<<<256, 256, 0, stream>>>(v_raw, vs1, vs2, gv, bv, k_raw, vnF, lam_c);
  k_main<<<1024, 512, 0, stream>>>(APre, vnF, q_raw, lam_c, qs1, qs2, gq, bq, out);
}

// Round 12
// 134.326 us; speedup vs baseline: 1.0518x; 1.0518x over previous
//
#include <hip/hip_runtime.h>

using u16 = unsigned short;
using u32 = unsigned int;

typedef __attribute__((ext_vector_type(4))) float f32x4;
typedef __attribute__((ext_vector_type(4))) u16 u16x4;
typedef __attribute__((ext_vector_type(8))) u16 u16x8;
typedef __attribute__((ext_vector_type(8))) short s16x8;

__device__ __forceinline__ u16 f2bf(float f) {
  u32 x = __builtin_bit_cast(u32, f);
  x += 0x7fffu + ((x >> 16) & 1u);
  return (u16)(x >> 16);
}
__device__ __forceinline__ float bf2f(u16 u) {
  u32 x = ((u32)u) << 16;
  return __builtin_bit_cast(float, x);
}

// async global->LDS, 16B per lane. dst must be wave-uniform; HW adds lane*16.
__device__ __forceinline__ void glds16(const u16* gsrc, u16* ldst) {
  __builtin_amdgcn_global_load_lds(
      (const __attribute__((address_space(1))) unsigned int*)gsrc,
      (__attribute__((address_space(3))) unsigned int*)ldst, 16, 0, 0);
}

// ---------------------------------------------------------------------------
// K_prep: blk<129 also zeros the atomic-accumulator region (lam_c..vs2,
// 33024 contiguous f32) -- replaces the hipMemsetAsync dispatch (runs before
// k_proj/k_nl atomics in stream order). blk<144 -> Wb row; blk>=144 -> APre.
// ---------------------------------------------------------------------------
__global__ __launch_bounds__(256) void k_prep(
    const float* __restrict__ wq, const float* __restrict__ wk,
    const float* __restrict__ wv, const float* __restrict__ R,
    u16* __restrict__ Wb, u16* __restrict__ APre, float* __restrict__ zbuf)
{
  const int blk = blockIdx.x;
  const int t = threadIdx.x;
  if (blk < 129) zbuf[blk * 256 + t] = 0.f;   // 129*256 = 33024 floats
  if (blk < 144) {
    const int o = blk;
    const float* src = (o < 64) ? (wq + o * 256)
                     : (o < 80) ? (wk + (o - 64) * 256)
                                : (wv + (o - 80) * 256);
    Wb[o * 256 + t] = f2bf(src[t]);
  } else {
    const int di = blk - 144;
    const int w = t >> 6, l = t & 63;
    const int g = l >> 4, k = l & 15;
    for (int j1 = w; j1 < 32; j1 += 4) {
      u16x8 o8;
#pragma unroll
      for (int e = 0; e < 8; ++e) {
        int dj = 8 * g + e - j1 + 31;
        o8[e] = f2bf(R[(di * 63 + dj) * 16 + k]);
      }
      *(u16x8*)(APre + ((di * 32 + j1) * 64 + l) * 8) = o8;
    }
  }
}

// ---------------------------------------------------------------------------
// K1: 1x1 conv projections via MFMA + fused BN partial sums for q,v.
// ---------------------------------------------------------------------------
union ProjSmem {
  u16 XLb[64][264];
  float SS[2][160];
};

__global__ __launch_bounds__(256) void k_proj(
    const float* __restrict__ x, const u16* __restrict__ Wb,
    float* __restrict__ q_raw, float* __restrict__ k_raw,
    float* __restrict__ v_raw,
    float* __restrict__ qs1, float* __restrict__ qs2,
    float* __restrict__ vs1, float* __restrict__ vs2)
{
  __shared__ ProjSmem PS;
  const int b  = blockIdx.x >> 4;
  const int p0 = (blockIdx.x & 15) * 64;
  const int t  = threadIdx.x;

  {
    const int p4 = (t & 15) * 4;
    const int cb = (t >> 4);
#pragma unroll
    for (int i = 0; i < 8; ++i) {
      const int c = 2 * (i * 16 + cb);
      f32x4 xa = *(const f32x4*)&x[(b * 256 + c) * 1024 + p0 + p4];
      f32x4 xb = *(const f32x4*)&x[(b * 256 + c + 1) * 1024 + p0 + p4];
#pragma unroll
      for (int j = 0; j < 4; ++j) {
        u32 pk = (u32)f2bf(xa[j]) | ((u32)f2bf(xb[j]) << 16);
        *(u32*)&PS.XLb[p4 + j][c] = pk;
      }
    }
  }
  __syncthreads();

  const int w  = t >> 6;
  const int l  = t & 63;
  const int g  = l >> 4;
  const int cc = l & 15;
  const int p  = p0 + w * 16 + cc;

  f32x4 acc[9];
  const f32x4 fz = {0.f, 0.f, 0.f, 0.f};
#pragma unroll
  for (int mt = 0; mt < 9; ++mt) acc[mt] = fz;

#pragma unroll
  for (int ko = 0; ko < 8; ++ko) {
    s16x8 bfr = *(const s16x8*)&PS.XLb[w * 16 + cc][ko * 32 + g * 8];
#pragma unroll
    for (int mt = 0; mt < 9; ++mt) {
      s16x8 afr = *(const s16x8*)&Wb[(mt * 16 + cc) * 256 + ko * 32 + g * 8];
      acc[mt] = __builtin_amdgcn_mfma_f32_16x16x32_bf16(afr, bfr, acc[mt], 0, 0, 0);
    }
  }

#pragma unroll
  for (int mt = 0; mt < 9; ++mt) {
#pragma unroll
    for (int r = 0; r < 4; ++r) {
      const int o = mt * 16 + 4 * g + r;
      const float val = acc[mt][r];
      if (mt < 4)       q_raw[(b * 64 + o) * 1024 + p] = val;
      else if (mt == 4) k_raw[(b * 16 + (o - 64)) * 1024 + p] = val;
      else              v_raw[(b * 64 + (o - 80)) * 1024 + p] = val;
    }
  }

  // ---- fused BN stats epilogue (q: mt 0..3, v: mt 5..8)
  __syncthreads();   // all XLb reads done; reuse LDS as SS
  {
    float* ss = &PS.SS[0][0];
    for (int i = t; i < 320; i += 256) ss[i] = 0.f;
  }
  __syncthreads();
#pragma unroll
  for (int mt = 0; mt < 9; ++mt) {
    if (mt == 4) continue;
#pragma unroll
    for (int r = 0; r < 4; ++r) {
      float s1 = acc[mt][r];
      float s2 = s1 * s1;
#pragma unroll
      for (int off = 1; off < 16; off <<= 1) {
        s1 += __shfl_xor(s1, off);
        s2 += __shfl_xor(s2, off);
      }
      if (cc == 0) {
        const int o = mt * 16 + 4 * g + r;
        atomicAdd(&PS.SS[0][o], s1);
        atomicAdd(&PS.SS[1][o], s2);
      }
    }
  }
  __syncthreads();
  if (t < 64) {
    atomicAdd(&qs1[t], PS.SS[0][t]);
    atomicAdd(&qs2[t], PS.SS[1][t]);
  } else if (t >= 80 && t < 144) {
    atomicAdd(&vs1[t - 80], PS.SS[0][t]);
    atomicAdd(&vs2[t - 80], PS.SS[1][t]);
  }
}

// ---------------------------------------------------------------------------
// K_nl2: fused k-softmax stats (in-block; k_raw is 2MB L2-resident so the
// 8x re-read is ~free) + V-normalize + vnF write + lam_c partial.
// ---------------------------------------------------------------------------
__global__ __launch_bounds__(256) void k_nl(
    const float* __restrict__ v_raw,
    const float* __restrict__ vs1, const float* __restrict__ vs2,
    const float* __restrict__ gv, const float* __restrict__ bv,
    const float* __restrict__ k_raw,
    u16* __restrict__ vnF, float* __restrict__ lam_c)
{
  __shared__ float VN[64][136];
  __shared__ float KE[16][132];
  __shared__ float KMX[16], KIV[16];
  const int b  = blockIdx.x >> 3;
  const int m0 = (blockIdx.x & 7) * 128;
  const int t  = threadIdx.x;
  const int wv4 = t >> 6, lane = t & 63;

  // ---- full-row softmax stats for this b's 16 k-rows (one wave per row)
  for (int rr = wv4; rr < 16; rr += 4) {
    const int row = b * 16 + rr;
    const f32x4* kr4 = (const f32x4*)(k_raw + row * 1024 + lane * 16);
    f32x4 a0 = kr4[0], a1 = kr4[1], a2 = kr4[2], a3 = kr4[3];
    float mx = -3.0e38f;
#pragma unroll
    for (int j = 0; j < 4; ++j)
      mx = fmaxf(mx, fmaxf(fmaxf(a0[j], a1[j]), fmaxf(a2[j], a3[j])));
#pragma unroll
    for (int off = 32; off; off >>= 1) mx = fmaxf(mx, __shfl_xor(mx, off));
    float s = 0.f;
#pragma unroll
    for (int j = 0; j < 4; ++j)
      s += __expf(a0[j] - mx) + __expf(a1[j] - mx)
         + __expf(a2[j] - mx) + __expf(a3[j] - mx);
#pragma unroll
    for (int off = 32; off; off >>= 1) s += __shfl_xor(s, off);
    if (lane == 0) { KMX[rr] = mx; KIV[rr] = 1.0f / s; }
  }

  // ---- V-normalize + vnF write (independent of stats; before barrier)
  {
    const int v = t & 63, mseg = t >> 6;   // 32 m per thread
    const float invN = 1.0f / 32768.0f;
    const float mu = vs1[v] * invN;
    const float var = vs2[v] * invN - mu * mu;
    const float sc = rsqrtf(var + 1e-5f) * gv[v];
    const float bi = bv[v] - mu * sc;
    const int i2 = (m0 >> 5) + mseg;
    const float* src = v_raw + (b * 64 + v) * 1024 + i2 * 32;
    u16* dstF = vnF + ((b * 32 + i2) * 4 + (v >> 4)) * 512 + (v & 15) * 8;
#pragma unroll
    for (int lg = 0; lg < 4; ++lg) {
      f32x4 a = *(const f32x4*)(src + lg * 8);
      f32x4 c = *(const f32x4*)(src + lg * 8 + 4);
      f32x4 na, nc;
      u16x8 o8;
#pragma unroll
      for (int j = 0; j < 4; ++j) {
        na[j] = a[j] * sc + bi;
        nc[j] = c[j] * sc + bi;
        o8[j] = f2bf(na[j]);
        o8[4 + j] = f2bf(nc[j]);
      }
      *(f32x4*)&VN[v][mseg * 32 + lg * 8] = na;
      *(f32x4*)&VN[v][mseg * 32 + lg * 8 + 4] = nc;
      *(u16x8*)(dstF + lg * 128) = o8;
    }
  }
  __syncthreads();   // KMX/KIV + VN visible

  // ---- KE for this m-chunk using in-block stats
  {
    const int kc = t >> 4, mm = (t & 15) * 8;
    const float* kr = k_raw + (b * 16 + kc) * 1024 + m0 + mm;
    const float mx = KMX[kc], iv = KIV[kc];
#pragma unroll
    for (int j = 0; j < 8; ++j) KE[kc][mm + j] = __expf(kr[j] - mx) * iv;
  }
  __syncthreads();

  const int kc = t & 15, vg = t >> 4;
  float acc[4] = {0.f, 0.f, 0.f, 0.f};
  for (int m4 = 0; m4 < 128; m4 += 4) {
    f32x4 ke = *(const f32x4*)&KE[kc][m4];
#pragma unroll
    for (int j = 0; j < 4; ++j) {
      f32x4 vv = *(const f32x4*)&VN[vg * 4 + j][m4];
      acc[j] += ke[0] * vv[0] + ke[1] * vv[1] + ke[2] * vv[2] + ke[3] * vv[3];
    }
  }
#pragma unroll
  for (int j = 0; j < 4; ++j)
    atomicAdd(&lam_c[(b * 16 + kc) * 64 + vg * 4 + j], acc[j]);
}

// ---------------------------------------------------------------------------
// K4 v9 (best-known k_main, measured 79.0-79.4us five times): BK=128
// phases, 4 i2-subs per barrier, B via glds dbuf, rolling P/Q A-prefetch,
// vmcnt(4) at the barrier, YL overlaid on BB. Plateau documented: eight
// structural variants (occupancy, barrier count, schedule depth, byte cuts
// via b-pair regs / row-pair LDS slabs / barrier-free regs) all land
// 79-100us; phase-wall ~= 2.5x MFMA content in every barrier-coupled form.
// Remaining unproven lever: 32x32x16 M-fold (halve instruction count).
// ---------------------------------------------------------------------------
__device__ __forceinline__ void load_a4(s16x8 (&dst)[4], const u16* ab)
{
#pragma unroll
  for (int j = 0; j < 4; ++j) dst[j] = *(const s16x8*)(ab + j * 512);
}

union KMainSmem {
  u16 BB[2][8192];     // 32 KB main-loop B double buffer
  float YL[256][18];   // 18 KB epilogue transpose buffer (overlaid)
};

__global__ __launch_bounds__(256, 4) void k_main(
    const u16* __restrict__ APre, const u16* __restrict__ vnF,
    const float* __restrict__ q_raw, const float* __restrict__ lam_c,
    const float* __restrict__ qs1, const float* __restrict__ qs2,
    const float* __restrict__ gq, const float* __restrict__ bq,
    float* __restrict__ out)
{
  __shared__ alignas(16) KMainSmem S;
  __shared__ float QL[64][17];    // BN-folded q: [o][j1loc 0..15]
  const int bid  = blockIdx.x;
  const int xcd  = bid & 7;
  const int sb   = bid >> 3;
  const int b    = xcd * 4 + (sb & 3);  // 4 consecutive b's per XCD
  const int rest = sb >> 2;             // 0..63
  const int i1   = rest >> 1;
  const int half = rest & 1;
  const int t  = threadIdx.x;
  const int w  = t >> 6;
  const int l  = t & 63;
  const int g  = l >> 4;
  const int c  = l & 15;
  const int j1base = half * 16 + w * 4;

  const u16* vF = vnF + b * 65536;     // 32 i2 * 2048 u16 per b

  f32x4 acc[4][4];
  const f32x4 fz = {0.f, 0.f, 0.f, 0.f};
#pragma unroll
  for (int nn = 0; nn < 4; ++nn)
#pragma unroll
    for (int tt = 0; tt < 4; ++tt) acc[nn][tt] = fz;

  // ---- prologue: QL staging (inline BN fold) + phase-0 B via glds
  {
    const int o = t >> 2, ns = (t & 3) * 4;
    const float invN = 1.0f / 32768.0f;
    const float mu = qs1[o] * invN;
    const float var = qs2[o] * invN - mu * mu;
    const float rs = rsqrtf(var + 1e-5f);
    const float sc = rs * gq[o];
    const float bi = bq[o] - mu * sc;
    f32x4 qa = *(const f32x4*)&q_raw[(b * 64 + o) * 1024 + i1 * 32 + half * 16 + ns];
#pragma unroll
    for (int j = 0; j < 4; ++j) QL[o][ns + j] = qa[j] * sc + bi;
  }
  {
    const u16* src = vF + w * 2048 + l * 8;   // per-lane global source
    u16* dst = &S.BB[0][w * 2048];            // wave-uniform LDS base
#pragma unroll
    for (int j = 0; j < 4; ++j) glds16(src + j * 512, dst + j * 512);
  }

  // first A-frag group: phase 0, sub 0 (i2 = 0)
  s16x8 afrP[4], afrQ[4];
  const u16* aBase = APre + ((31 - i1) * 32 + j1base) * 512 + l * 8;
  load_a4(afrP, aBase);
  __syncthreads();   // drains vmcnt(0)+lgkmcnt(0): glds + QL writes visible

  for (int p = 0; p < 8; ++p) {
    const int cur = p & 1;
    const bool pf = (p < 7);
    if (pf) {
      // B glds for phase p+1, issued FIRST (oldest outstanding vmem)
      const u16* src = vF + (p + 1) * 8192 + w * 2048 + l * 8;
      u16* dst = &S.BB[cur ^ 1][w * 2048];
#pragma unroll
      for (int j = 0; j < 4; ++j) glds16(src + j * 512, dst + j * 512);
    }
    __builtin_amdgcn_sched_barrier(0);  // pin glds-issue before A-issues
    const u16* ap = aBase + 4 * p * 16384;   // 16384 u16 per i2-slice
    s16x8 bfr[4];
#pragma unroll
    for (int s = 0; s < 4; ++s) {
#pragma unroll
      for (int tt = 0; tt < 4; ++tt)
        bfr[tt] = *(const s16x8*)&S.BB[cur][s * 2048 + tt * 512 + l * 8];
      // rolling A prefetch: next sub (or next phase's sub 0)
      if (s < 3) {
        if (s & 1) load_a4(afrP, ap + (s + 1) * 16384);
        else       load_a4(afrQ, ap + (s + 1) * 16384);
      } else if (pf) {
        load_a4(afrP, ap + 4 * 16384);
      }
      const s16x8* A = (s & 1) ? afrQ : afrP;
#pragma unroll
      for (int nn = 0; nn < 4; ++nn)
#pragma unroll
        for (int tt = 0; tt < 4; ++tt)
          acc[nn][tt] = __builtin_amdgcn_mfma_f32_16x16x32_bf16(
              A[nn], bfr[tt], acc[nn][tt], 0, 0, 0);
    }
    // glds (oldest in FIFO) provably complete once sub-3's auto-wait drains
    // to the last A-group; vmcnt(4) keeps those 4 A-loads in flight.
    asm volatile("s_waitcnt vmcnt(4)" ::: "memory");
    __builtin_amdgcn_sched_barrier(0);
    __builtin_amdgcn_s_barrier();
    __builtin_amdgcn_sched_barrier(0);
  }

  // ---- epilogue: pre-add lam_c into acc, contract with q, transpose, store
  // (BB is dead after the final barrier; YL overlays it.)
  {
    const float* lcb = lam_c + b * 1024;
#pragma unroll
    for (int tt = 0; tt < 4; ++tt)
#pragma unroll
      for (int r = 0; r < 4; ++r) {
        const float lv = lcb[(4 * g + r) * 64 + tt * 16 + c];
#pragma unroll
        for (int nn = 0; nn < 4; ++nn) acc[nn][tt][r] += lv;
      }
  }
#pragma unroll
  for (int nn = 0; nn < 4; ++nn) {
    const int j1loc = w * 4 + nn;
#pragma unroll
    for (int h = 0; h < 4; ++h) {
      const float q0 = QL[h * 16 + 4 * g + 0][j1loc];
      const float q1 = QL[h * 16 + 4 * g + 1][j1loc];
      const float q2 = QL[h * 16 + 4 * g + 2][j1loc];
      const float q3 = QL[h * 16 + 4 * g + 3][j1loc];
#pragma unroll
      for (int tt = 0; tt < 4; ++tt) {
        float sY = q0 * acc[nn][tt][0] + q1 * acc[nn][tt][1]
                 + q2 * acc[nn][tt][2] + q3 * acc[nn][tt][3];
        sY += __shfl_xor(sY, 16);
        sY += __shfl_xor(sY, 32);
        if (g == h) S.YL[h * 64 + tt * 16 + c][j1loc] = sY;
      }
    }
  }
  __syncthreads();
#pragma unroll
  for (int it = 0; it < 4; ++it) {
    const int o  = (t >> 2) + it * 64;
    const int nf = (t & 3) * 4;
    f32x4 v4 = *(const f32x4*)&S.YL[o][nf];
    *(f32x4*)&out[(b * 256 + o) * 1024 + i1 * 32 + half * 16 + nf] = v4;
  }
}

// ---------------------------------------------------------------------------
extern "C" void kernel_launch(void* const* d_in, const int* in_sizes, int n_in,
                              void* d_out, int out_size, void* d_ws, size_t ws_size,
                              hipStream_t stream) {
  const float* x  = (const float*)d_in[0];
  const float* wq = (const float*)d_in[1];
  const float* wk = (const float*)d_in[2];
  const float* wv = (const float*)d_in[3];
  const float* gq = (const float*)d_in[4];
  const float* bq = (const float*)d_in[5];
  const float* gv = (const float*)d_in[6];
  const float* bv = (const float*)d_in[7];
  const float* R  = (const float*)d_in[8];
  float* out = (float*)d_out;

  float* wsf   = (float*)d_ws;
  float* q_raw = wsf;                     // 32*64*1024 f32
  float* k_raw = q_raw + 32 * 64 * 1024;  // 32*16*1024
  float* v_raw = k_raw + 32 * 16 * 1024;  // 32*64*1024
  float* lam_c = v_raw + 32 * 64 * 1024;  // 32*16*64 (atomic dst, zeroed by k_prep)
  float* qs1   = lam_c + 32 * 16 * 64;
  float* qs2   = qs1 + 64;
  float* vs1   = qs2 + 64;
  float* vs2   = vs1 + 64;
  float* kmax  = vs2 + 64;                // 512 (unused, keeps offsets stable)
  float* kinv  = kmax + 512;              // 512 (unused)
  u16*   vn    = (u16*)(kinv + 512);      // (unused slot, keeps offsets stable)
  u16*   vnF   = vn + 32 * 64 * 1024;     // 32*65536 u16 (fragment-linear)
  u16*   APre  = vnF + 32 * 65536;        // 63*32*512 u16
  u16*   Wb    = APre + 63 * 32 * 512;    // 144*256 u16

  k_prep<<<207, 256, 0, stream>>>(wq, wk, wv, R, Wb, APre, lam_c);
  k_proj<<<512, 256, 0, stream>>>(x, Wb, q_raw, k_raw, v_raw, qs1, qs2, vs1, vs2);
  k_nl<<<256, 256, 0, stream>>>(v_raw, vs1, vs2, gv, bv, k_raw, vnF, lam_c);
  k_main<<<2048, 256, 0, stream>>>(APre, vnF, q_raw, lam_c, qs1, qs2, gq, bq, out);
}